// Round 11
// baseline (707.769 us; speedup 1.0000x reference)
//
#include <hip/hip_runtime.h>
#include <stdint.h>

typedef unsigned short u16;
typedef unsigned int u32;
typedef __attribute__((ext_vector_type(8))) short short8;
typedef __attribute__((ext_vector_type(8))) u16 us8;
typedef __attribute__((ext_vector_type(4))) u16 us4;
typedef __attribute__((ext_vector_type(4))) float f32x4;

constexpr int NB = 2;
constexpr int SEQ = 2048;
constexpr int DIM = 1024;
constexpr int NH = 16;
constexpr int HD = 64;
constexpr int NE = 8;
constexpr int FF = 2048;
constexpr int TOK = NB * SEQ;      // 4096
constexpr int NQKV = 1536;         // q[0:1024) k[1024:1280) v[1280:1536)
constexpr int NPAIR = TOK * 2;     // 8192
constexpr float REPS = 1e-5f;

__device__ __forceinline__ u16 f2bf(float x) {
  union { float f; u32 u; } v; v.f = x;
  u32 r = v.u + 0x7fffu + ((v.u >> 16) & 1u);
  return (u16)(r >> 16);
}
__device__ __forceinline__ float bf2f(u16 h) {
  union { u32 u; float f; } v; v.u = ((u32)h) << 16;
  return v.f;
}

// async global->LDS, 16B per lane (HW: wave-uniform LDS base + lane*16)
__device__ __forceinline__ void gl_lds16(const u16* g, u16* l) {
  __builtin_amdgcn_global_load_lds(
      (const __attribute__((address_space(1))) void*)g,
      (__attribute__((address_space(3))) void*)l, 16, 0, 0);
}

// ---------------- weight transpose + fp32->bf16 (optionally split hi/lo) ----
template <bool SPLIT>
__global__ __launch_bounds__(256) void tcvt_k(const float* __restrict__ src,
                                              u16* __restrict__ dhi,
                                              u16* __restrict__ dlo,
                                              int K, int N) {
  int z = blockIdx.z;
  src += (size_t)z * K * N;
  dhi += (size_t)z * K * N;
  if (SPLIT) dlo += (size_t)z * K * N;
  int n0 = blockIdx.x * 64, k0 = blockIdx.y * 64;
  __shared__ float tile[64][65];
  int t = threadIdx.x;
  int kk = t >> 4, nn4 = (t & 15) * 4;
#pragma unroll
  for (int i = 0; i < 4; i++) {
    int k = kk + i * 16;
    const float* p = src + (size_t)(k0 + k) * N + n0 + nn4;
    float4 v = *(const float4*)p;
    tile[nn4 + 0][k] = v.x;
    tile[nn4 + 1][k] = v.y;
    tile[nn4 + 2][k] = v.z;
    tile[nn4 + 3][k] = v.w;
  }
  __syncthreads();
  int nn = t >> 4, k4 = (t & 15) * 4;
#pragma unroll
  for (int i = 0; i < 4; i++) {
    int n = nn + i * 16;
    us4 hi, lo;
#pragma unroll
    for (int j = 0; j < 4; j++) {
      float f = tile[n][k4 + j];
      u16 h = f2bf(f);
      hi[j] = h;
      if (SPLIT) lo[j] = f2bf(f - bf2f(h));
    }
    *(us4*)(dhi + (size_t)(n0 + n) * K + k0 + k4) = hi;
    if (SPLIT) *(us4*)(dlo + (size_t)(n0 + n) * K + k0 + k4) = lo;
  }
}

// ---------------- rmsnorm (fp32 in, bf16 out, optional split) ---------------
template <bool SPLIT>
__global__ __launch_bounds__(256) void rmsnorm_k(const float* __restrict__ x,
                                                 const float* __restrict__ w,
                                                 u16* __restrict__ ohi,
                                                 u16* __restrict__ olo) {
  int row = blockIdx.x, t = threadIdx.x;
  float4 v = *(const float4*)(x + (size_t)row * DIM + t * 4);
  float ss = v.x * v.x + v.y * v.y + v.z * v.z + v.w * v.w;
#pragma unroll
  for (int m = 1; m < 64; m <<= 1) ss += __shfl_xor(ss, m);
  __shared__ float red[4];
  if ((t & 63) == 0) red[t >> 6] = ss;
  __syncthreads();
  float rstd = rsqrtf((red[0] + red[1] + red[2] + red[3]) * (1.0f / DIM) + REPS);
  float4 wv = *(const float4*)(w + t * 4);
  float os[4] = {v.x * rstd * wv.x, v.y * rstd * wv.y, v.z * rstd * wv.z,
                 v.w * rstd * wv.w};
  us4 hi, lo;
#pragma unroll
  for (int j = 0; j < 4; j++) {
    u16 h = f2bf(os[j]);
    hi[j] = h;
    if (SPLIT) lo[j] = f2bf(os[j] - bf2f(h));
  }
  *(us4*)(ohi + (size_t)row * DIM + t * 4) = hi;
  if (SPLIT) *(us4*)(olo + (size_t)row * DIM + t * 4) = lo;
}

// ---------------- MFMA GEMM: m97 structure + XCD-chunked order + K-split ----
// LDS rows of 8 chunks x 16B; chunk position p of row r holds global chunk
// p^(r&7) (pre-swizzled source, linear LDS dest; conflict-free).
// 4 waves (2x2). XCD-chunked item order (blockIdx%8 = XCD owns contiguous
// range). NKS: K-split factor (only valid with atomic epilogue EPI=3).
// PERSIST: grid-strides over plan[] items. GATHER: A rows via pids (MoE).
template <int EPI, bool SPLIT, bool DUAL, bool PERSIST, bool GATHER, int NXL,
          int NT, int BN, int NKS, int MINW>
__global__ __launch_bounds__(256, MINW) void gemm_k(
    const u16* __restrict__ Ah, const u16* __restrict__ Al,
    const u16* __restrict__ Bh, const u16* __restrict__ Bl,
    const u16* __restrict__ Bd, int N, int ldc,
    float* __restrict__ Cf, u16* __restrict__ Cb, float* __restrict__ C2,
    const float* __restrict__ resid, const int* __restrict__ cnt,
    const int* __restrict__ pids, const float* __restrict__ pw,
    const int* __restrict__ plan) {
  constexpr int K = NT * 64;    // per-slice K
  constexpr int KT = K * NKS;   // full K (row stride)
  constexpr int WCOL = BN / 2;
  constexpr int FN = BN / 32;   // B frags per wave; also B staging iters

  int tid = threadIdx.x, lane = tid & 63, wid = tid >> 6;
  int wm = wid >> 1, wn = wid & 1;
  int rr = lane & 15, g = lane >> 4;

  __shared__ u16 sAh[128 * 64];
  __shared__ u16 sAl[SPLIT ? 128 * 64 : 16];
  __shared__ u16 sBh[BN * 64];
  __shared__ u16 sBl[SPLIT ? BN * 64 : 16];
  __shared__ u16 sB1[DUAL ? BN * 64 : 16];
  __shared__ int spid[PERSIST ? 128 : 8];
  __shared__ int srow[GATHER ? 128 : 8];

  int pl[9];
  int items;
  if (PERSIST) {
#pragma unroll
    for (int e = 0; e < 9; e++) pl[e] = plan[e];
    items = pl[8] << NXL;
  } else {
    items = 1;
  }

  // XCD-chunked virtual id: blocks on XCD i (blockIdx%8==i) process a
  // contiguous item/tile range. Requires grid size % 8 == 0 (all ours are).
  int it0, itstep;
  if (PERSIST) {
    int nb = gridDim.x;
    it0 = ((nb & 7) == 0) ? ((blockIdx.x & 7) * (nb >> 3) + (blockIdx.x >> 3))
                          : blockIdx.x;
    itstep = nb;
  } else {
    it0 = 0;
    itstep = 1;
  }
  for (int w = it0; w < items; w += itstep) {
    int m0, n0, z, yt, cntz, ks;
    if (PERSIST) {
      int wy = w >> NXL;
      int sub = w & ((1 << NXL) - 1);
      int x = sub / NKS;
      ks = sub % NKS;
      z = 0;
#pragma unroll
      for (int e = 1; e < 8; e++) z += (wy >= pl[e]) ? 1 : 0;
      yt = wy - pl[z];
      m0 = wy * 128;  // dense row base
      n0 = x * BN;
      cntz = cnt[z];
      __syncthreads();  // previous item done with spid/srow + LDS
      if (tid < 128) {
        int i = yt * 128 + tid;
        if (i > cntz - 1) i = cntz - 1;
        int p = pids[z * NPAIR + i];
        spid[tid] = p;
        if (GATHER) srow[tid] = p >> 1;
      }
      __syncthreads();
    } else {
      int gx = gridDim.x;
      int nb = gx * gridDim.y;
      int lin = blockIdx.y * gx + blockIdx.x;
      int v = ((nb & 7) == 0) ? ((lin & 7) * (nb >> 3) + (lin >> 3)) : lin;
      m0 = (v / gx) * 128;
      n0 = (v % gx) * BN;
      z = 0;
      yt = 0;
      cntz = 1 << 30;
      ks = 0;
    }

    const u16* Bhz = Bh + (size_t)z * N * KT;
    const u16* Blz = SPLIT ? Bl + (size_t)z * N * KT : nullptr;
    const u16* Bdz = DUAL ? Bd + (size_t)z * N * KT : nullptr;
    int kbase = ks * K;

    // staging descriptors (pre-swizzled global source, linear LDS dest)
    const u16 *agh[4], *agl[SPLIT ? 4 : 1];
    int aoff[4];
#pragma unroll
    for (int i = 0; i < 4; i++) {
      int cid = tid + i * 256;
      int r = cid >> 3, c = cid & 7;
      int gr = GATHER ? srow[r] : (m0 + r);
      int sc = c ^ (r & 7);
      agh[i] = Ah + (size_t)gr * KT + kbase + sc * 8;
      if (SPLIT) agl[i] = Al + (size_t)gr * KT + kbase + sc * 8;
      aoff[i] = r * 64 + c * 8;
    }
    const u16 *bgh[FN], *bgl[SPLIT ? FN : 1], *bg1[DUAL ? FN : 1];
    int boff[FN];
#pragma unroll
    for (int i = 0; i < FN; i++) {
      int cid = tid + i * 256;
      int r = cid >> 3, c = cid & 7;
      int sc = c ^ (r & 7);
      size_t gr = (size_t)(n0 + r) * KT + kbase + sc * 8;
      bgh[i] = Bhz + gr;
      if (SPLIT) bgl[i] = Blz + gr;
      if (DUAL) bg1[i] = Bdz + gr;
      boff[i] = r * 64 + c * 8;
    }

    f32x4 zv = {0.f, 0.f, 0.f, 0.f};
    f32x4 acc[4][FN];
    f32x4 acc1[DUAL ? 4 : 1][DUAL ? FN : 1];
#pragma unroll
    for (int a = 0; a < 4; a++)
#pragma unroll
      for (int b = 0; b < FN; b++) {
        acc[a][b] = zv;
        if (DUAL) acc1[a][b] = zv;
      }

    for (int t = 0; t < NT; t++) {
      int k0 = t * 64;
      __syncthreads();  // previous compute done reading LDS
#pragma unroll
      for (int i = 0; i < 4; i++) {
        gl_lds16(agh[i] + k0, sAh + aoff[i]);
        if (SPLIT) gl_lds16(agl[i] + k0, sAl + aoff[i]);
      }
#pragma unroll
      for (int i = 0; i < FN; i++) {
        gl_lds16(bgh[i] + k0, sBh + boff[i]);
        if (SPLIT) gl_lds16(bgl[i] + k0, sBl + boff[i]);
        if (DUAL) gl_lds16(bg1[i] + k0, sB1 + boff[i]);
      }
      __syncthreads();  // compiler drains vmcnt(0) before this barrier

#pragma unroll
      for (int kc = 0; kc < 2; kc++) {
        short8 a_h[4], a_l[SPLIT ? 4 : 1], b_h[FN], b_l[SPLIT ? FN : 1],
            b1f[DUAL ? FN : 1];
#pragma unroll
        for (int f = 0; f < 4; f++) {
          int ra = wm * 64 + f * 16 + rr;
          int off = ra * 64 + (((kc * 4 + g) ^ (ra & 7)) * 8);
          a_h[f] = *(const short8*)&sAh[off];
          if (SPLIT) a_l[f] = *(const short8*)&sAl[off];
        }
#pragma unroll
        for (int f = 0; f < FN; f++) {
          int rb = wn * WCOL + f * 16 + rr;
          int off = rb * 64 + (((kc * 4 + g) ^ (rb & 7)) * 8);
          b_h[f] = *(const short8*)&sBh[off];
          if (SPLIT) b_l[f] = *(const short8*)&sBl[off];
          if (DUAL) b1f[f] = *(const short8*)&sB1[off];
        }
#pragma unroll
        for (int fm = 0; fm < 4; fm++)
#pragma unroll
          for (int fn = 0; fn < FN; fn++) {
            acc[fm][fn] = __builtin_amdgcn_mfma_f32_16x16x32_bf16(
                a_h[fm], b_h[fn], acc[fm][fn], 0, 0, 0);
            if (SPLIT) {
              acc[fm][fn] = __builtin_amdgcn_mfma_f32_16x16x32_bf16(
                  a_h[fm], b_l[fn], acc[fm][fn], 0, 0, 0);
              acc[fm][fn] = __builtin_amdgcn_mfma_f32_16x16x32_bf16(
                  a_l[fm], b_h[fn], acc[fm][fn], 0, 0, 0);
            }
            if (DUAL)
              acc1[fm][fn] = __builtin_amdgcn_mfma_f32_16x16x32_bf16(
                  a_h[fm], b1f[fn], acc1[fm][fn], 0, 0, 0);
          }
      }
    }

    // epilogue: C frag layout col=lane&15, row=(lane>>4)*4+reg
#pragma unroll
    for (int fm = 0; fm < 4; fm++)
#pragma unroll
      for (int fn = 0; fn < FN; fn++)
#pragma unroll
        for (int rg = 0; rg < 4; rg++) {
          int rl = wm * 64 + fm * 16 + g * 4 + rg;
          int col = n0 + wn * WCOL + fn * 16 + rr;
          float v = acc[fm][fn][rg];
          if (EPI == 0) {
            Cf[(size_t)(m0 + rl) * ldc + col] = v;
          } else if (EPI == 1) {
            size_t idx = (size_t)(m0 + rl) * ldc + col;
            float r2 = v + resid[idx];
            Cf[idx] = r2;
            C2[idx] = r2;
          } else if (EPI == 2) {
            float gg = v / (1.0f + __expf(-v));
            float o = gg * acc1[fm][fn][rg];
            Cb[(size_t)(m0 + rl) * ldc + col] = f2bf(o);
          } else {
            int i = yt * 128 + rl;
            if (i < cntz) {
              int p = spid[rl];
              atomicAdd(&Cf[(size_t)(p >> 1) * ldc + col], pw[p] * v);
            }
          }
        }
  }
}

// ---------------- RoPE (in-place on fp32 qkv: 16 q heads + 4 k heads) -------
__global__ __launch_bounds__(256) void rope_k(float* __restrict__ qkv,
                                              const float* __restrict__ fc,
                                              const float* __restrict__ fs) {
  int idx = blockIdx.x * 256 + threadIdx.x;
  int i = idx & 31;
  int hh = (idx >> 5) % 20;
  int t = idx / 640;
  if (t >= TOK) return;
  int s = t & (SEQ - 1);
  int base = (hh < 16) ? (hh * 64) : (1024 + (hh - 16) * 64);
  float c = fc[s * 32 + i], sn = fs[s * 32 + i];
  float* p = qkv + (size_t)t * NQKV + base + 2 * i;
  float xr = p[0], xi = p[1];
  p[0] = xr * c - xi * sn;
  p[1] = xr * sn + xi * c;
}

// ---------------- K/V convert to split bf16, pre-swizzled tile-major --------
__global__ __launch_bounds__(256) void cvtkv_k(const float* __restrict__ qkv,
                                               u16* __restrict__ Kh,
                                               u16* __restrict__ Kl,
                                               u16* __restrict__ Vh,
                                               u16* __restrict__ Vl) {
  int kvt = blockIdx.x;
  int kvh = blockIdx.y;
  int b = blockIdx.z;
  int t = threadIdx.x;
  __shared__ float vt[64][65];
  size_t tile = ((size_t)((b * 4 + kvh) * 32 + kvt)) * 4096;
  int r = t >> 2, c4 = t & 3;
  {
    const float* kp = qkv + ((size_t)(b * SEQ + kvt * 64 + r)) * NQKV + 1024 +
                      kvh * 64 + c4 * 16;
    float ff[16];
#pragma unroll
    for (int q = 0; q < 4; q++) {
      float4 f = *(const float4*)(kp + q * 4);
      ff[q * 4 + 0] = f.x; ff[q * 4 + 1] = f.y;
      ff[q * 4 + 2] = f.z; ff[q * 4 + 3] = f.w;
    }
#pragma unroll
    for (int half = 0; half < 2; half++) {
      int c = c4 * 2 + half;
      us8 hi, lo;
#pragma unroll
      for (int j = 0; j < 8; j++) {
        float f = ff[half * 8 + j];
        u16 h = f2bf(f);
        hi[j] = h;
        lo[j] = f2bf(f - bf2f(h));
      }
      int off = r * 64 + ((c ^ (r & 7)) * 8);
      *(us8*)(Kh + tile + off) = hi;
      *(us8*)(Kl + tile + off) = lo;
    }
  }
  {
    const float* vp = qkv + ((size_t)(b * SEQ + kvt * 64 + r)) * NQKV + 1280 +
                      kvh * 64 + c4 * 16;
#pragma unroll
    for (int q = 0; q < 4; q++) {
      float4 f = *(const float4*)(vp + q * 4);
      vt[r][c4 * 16 + q * 4 + 0] = f.x;
      vt[r][c4 * 16 + q * 4 + 1] = f.y;
      vt[r][c4 * 16 + q * 4 + 2] = f.z;
      vt[r][c4 * 16 + q * 4 + 3] = f.w;
    }
  }
  __syncthreads();
  {
    int d = t >> 2, g4 = t & 3;
    float ff[16];
#pragma unroll
    for (int j = 0; j < 16; j++) ff[j] = vt[g4 * 16 + j][d];
#pragma unroll
    for (int half = 0; half < 2; half++) {
      int c = g4 * 2 + half;
      us8 hi, lo;
#pragma unroll
      for (int j = 0; j < 8; j++) {
        float f = ff[half * 8 + j];
        u16 h = f2bf(f);
        hi[j] = h;
        lo[j] = f2bf(f - bf2f(h));
      }
      int off = d * 64 + ((c ^ (d & 7)) * 8);
      *(us8*)(Vh + tile + off) = hi;
      *(us8*)(Vl + tile + off) = lo;
    }
  }
}

// ---------------- flash attention (paired q-tiles, preconverted K/V) --------
__global__ __launch_bounds__(256, 2) void flash_k(
    const float* __restrict__ qkv, const u16* __restrict__ Kg,
    const u16* __restrict__ Klg, const u16* __restrict__ Vg,
    const u16* __restrict__ Vlg, u16* __restrict__ ah, u16* __restrict__ al) {
  int pi = blockIdx.x;
  int h = blockIdx.y;
  int b = blockIdx.z;
  int qt[2] = {31 - pi, pi};
  int kvh = h >> 2;
  int tid = threadIdx.x, lane = tid & 63, wid = tid >> 6;
  int rr = lane & 15, g = lane >> 4;

  __shared__ u16 sKh[4096], sKl[4096], sVh[4096], sVl[4096];
  __shared__ u32 sP[4][1024];

  f32x4 zv = {0.f, 0.f, 0.f, 0.f};
  short8 aqh[2][2], aql[2][2];
#pragma unroll
  for (int u = 0; u < 2; u++) {
    int qrow = qt[u] * 64 + wid * 16 + rr;
    const float* qp =
        qkv + ((size_t)(b * SEQ + qrow)) * NQKV + h * 64 + g * 8;
#pragma unroll
    for (int kc = 0; kc < 2; kc++) {
      float4 f0 = *(const float4*)(qp + kc * 32);
      float4 f1 = *(const float4*)(qp + kc * 32 + 4);
      float ff[8] = {f0.x, f0.y, f0.z, f0.w, f1.x, f1.y, f1.z, f1.w};
#pragma unroll
      for (int j = 0; j < 8; j++) {
        u16 hi = f2bf(ff[j]);
        aqh[u][kc][j] = (short)hi;
        aql[u][kc][j] = (short)f2bf(ff[j] - bf2f(hi));
      }
    }
  }

  f32x4 o[2][4];
  float m_r[2][4], l_r[2][4];
#pragma unroll
  for (int u = 0; u < 2; u++)
#pragma unroll
    for (int i = 0; i < 4; i++) {
      o[u][i] = zv;
      m_r[u][i] = -3.0e38f;
      l_r[u][i] = 0.f;
    }

  size_t tb = ((size_t)(b * 4 + kvh) * 32) * 4096;
  int so = tid * 16;
  us8 rKh[2], rKl[2], rVh[2], rVl[2];
  {
    size_t go = tb + so;
    rKh[0] = *(const us8*)(Kg + go);  rKh[1] = *(const us8*)(Kg + go + 8);
    rKl[0] = *(const us8*)(Klg + go); rKl[1] = *(const us8*)(Klg + go + 8);
    rVh[0] = *(const us8*)(Vg + go);  rVh[1] = *(const us8*)(Vg + go + 8);
    rVl[0] = *(const us8*)(Vlg + go); rVl[1] = *(const us8*)(Vlg + go + 8);
  }

  int nt = qt[0];
  for (int kvt = 0; kvt <= nt; kvt++) {
    __syncthreads();
    *(us8*)&sKh[so] = rKh[0]; *(us8*)&sKh[so + 8] = rKh[1];
    *(us8*)&sKl[so] = rKl[0]; *(us8*)&sKl[so + 8] = rKl[1];
    *(us8*)&sVh[so] = rVh[0]; *(us8*)&sVh[so + 8] = rVh[1];
    *(us8*)&sVl[so] = rVl[0]; *(us8*)&sVl[so + 8] = rVl[1];
    if (kvt < nt) {
      size_t go = tb + (size_t)(kvt + 1) * 4096 + so;
      rKh[0] = *(const us8*)(Kg + go);  rKh[1] = *(const us8*)(Kg + go + 8);
      rKl[0] = *(const us8*)(Klg + go); rKl[1] = *(const us8*)(Klg + go + 8);
      rVh[0] = *(const us8*)(Vg + go);  rVh[1] = *(const us8*)(Vg + go + 8);
      rVl[0] = *(const us8*)(Vlg + go); rVl[1] = *(const us8*)(Vlg + go + 8);
    }
    __syncthreads();

#pragma unroll
    for (int u = 0; u < 2; u++) {
      if (!(u == 1 && kvt > qt[1])) {
        float pv[4][4];
#pragma unroll
        for (int c16 = 0; c16 < 4; c16++) {
          int rk = c16 * 16 + rr;
          f32x4 sacc = zv;
#pragma unroll
          for (int kc = 0; kc < 2; kc++) {
            int sw = rk * 64 + (((kc * 4 + g) ^ (rk & 7)) * 8);
            short8 bh = *(const short8*)&sKh[sw];
            short8 bl = *(const short8*)&sKl[sw];
            sacc = __builtin_amdgcn_mfma_f32_16x16x32_bf16(aqh[u][kc], bh,
                                                           sacc, 0, 0, 0);
            sacc = __builtin_amdgcn_mfma_f32_16x16x32_bf16(aqh[u][kc], bl,
                                                           sacc, 0, 0, 0);
            sacc = __builtin_amdgcn_mfma_f32_16x16x32_bf16(aql[u][kc], bh,
                                                           sacc, 0, 0, 0);
          }
          bool diag = (kvt == qt[u]);
#pragma unroll
          for (int rg = 0; rg < 4; rg++) {
            float val = sacc[rg] * 0.125f;
            if (diag) {
              int kv_l = c16 * 16 + rr;
              int q_l = wid * 16 + g * 4 + rg;
              if (kv_l > q_l) val = -3.0e38f;
            }
            pv[c16][rg] = val;
          }
        }
        float pm[4];
#pragma unroll
        for (int rg = 0; rg < 4; rg++)
          pm[rg] = fmaxf(fmaxf(pv[0][rg], pv[1][rg]),
                         fmaxf(pv[2][rg], pv[3][rg]));
#pragma unroll
        for (int m = 1; m < 16; m <<= 1)
#pragma unroll
          for (int rg = 0; rg < 4; rg++)
            pm[rg] = fmaxf(pm[rg], __shfl_xor(pm[rg], m));
        float scl[4];
#pragma unroll
        for (int rg = 0; rg < 4; rg++) {
          float mn = fmaxf(m_r[u][rg], pm[rg]);
          scl[rg] = __expf(m_r[u][rg] - mn);
          m_r[u][rg] = mn;
        }
#pragma unroll
        for (int c16 = 0; c16 < 4; c16++)
#pragma unroll
          for (int rg = 0; rg < 4; rg++)
            pv[c16][rg] = __expf(pv[c16][rg] - m_r[u][rg]);
        float rsum[4];
#pragma unroll
        for (int rg = 0; rg < 4; rg++)
          rsum[rg] = pv[0][rg] + pv[1][rg] + pv[2][rg] + pv[3][rg];
#pragma unroll
        for (int m = 1; m < 16; m <<= 1)
#pragma unroll
          for (int rg = 0; rg < 4; rg++) rsum[rg] += __shfl_xor(rsum[rg], m);
#pragma unroll
        for (int rg = 0; rg < 4; rg++)
          l_r[u][rg] = l_r[u][rg] * scl[rg] + rsum[rg];
#pragma unroll
        for (int d16 = 0; d16 < 4; d16++)
#pragma unroll
          for (int rg = 0; rg < 4; rg++) o[u][d16][rg] *= scl[rg];

#pragma unroll
        for (int c16 = 0; c16 < 4; c16++)
#pragma unroll
          for (int rg = 0; rg < 4; rg++) {
            int ql = g * 4 + rg;
            int kvl = c16 * 16 + rr;
            u16 hi = f2bf(pv[c16][rg]);
            u16 lo = f2bf(pv[c16][rg] - bf2f(hi));
            sP[wid][ql * 64 + (kvl ^ (((ql >> 2) & 3) << 4))] =
                ((u32)lo << 16) | (u32)hi;
          }
        short8 pah[2], pal[2];
#pragma unroll
        for (int kc = 0; kc < 2; kc++) {
          int xb = (kc * 32 + g * 8) ^ (((rr >> 2) & 3) << 4);
          const u32* pp = &sP[wid][rr * 64 + xb];
#pragma unroll
          for (int j = 0; j < 8; j++) {
            u32 w = pp[j];
            pah[kc][j] = (short)(w & 0xffffu);
            pal[kc][j] = (short)(w >> 16);
          }
        }
#pragma unroll
        for (int d16 = 0; d16 < 4; d16++) {
          int rv = d16 * 16 + rr;
#pragma unroll
          for (int kc = 0; kc < 2; kc++) {
            int sw = rv * 64 + (((kc * 4 + g) ^ (rv & 7)) * 8);
            short8 vh = *(const short8*)&sVh[sw];
            short8 vl = *(const short8*)&sVl[sw];
            o[u][d16] = __builtin_amdgcn_mfma_f32_16x16x32_bf16(
                pah[kc], vh, o[u][d16], 0, 0, 0);
            o[u][d16] = __builtin_amdgcn_mfma_f32_16x16x32_bf16(
                pah[kc], vl, o[u][d16], 0, 0, 0);
            o[u][d16] = __builtin_amdgcn_mfma_f32_16x16x32_bf16(
                pal[kc], vh, o[u][d16], 0, 0, 0);
          }
        }
      }
    }
  }

#pragma unroll
  for (int u = 0; u < 2; u++)
#pragma unroll
    for (int rg = 0; rg < 4; rg++) {
      float inv = 1.0f / l_r[u][rg];
      int qr = qt[u] * 64 + wid * 16 + g * 4 + rg;
      size_t obase = (size_t)(b * SEQ + qr) * 1024 + h * 64;
#pragma unroll
      for (int d16 = 0; d16 < 4; d16++) {
        float v = o[u][d16][rg] * inv;
        u16 hi = f2bf(v);
        ah[obase + d16 * 16 + rr] = hi;
        al[obase + d16 * 16 + rr] = f2bf(v - bf2f(hi));
      }
    }
}

// ---------------- routing: fp32 rmsnorm + gate + top2 + atomic bucketing ----
__global__ __launch_bounds__(256) void route_k(const float* __restrict__ h,
                                               const float* __restrict__ wffn,
                                               const float* __restrict__ gw,
                                               int* __restrict__ cnt,
                                               int* __restrict__ pids,
                                               float* __restrict__ pw) {
  int t = blockIdx.x, tid = threadIdx.x;
  float4 v = *(const float4*)(h + (size_t)t * DIM + tid * 4);
  float ss = v.x * v.x + v.y * v.y + v.z * v.z + v.w * v.w;
#pragma unroll
  for (int m = 1; m < 64; m <<= 1) ss += __shfl_xor(ss, m);
  __shared__ float red[4];
  if ((tid & 63) == 0) red[tid >> 6] = ss;
  __syncthreads();
  float rstd = rsqrtf((red[0] + red[1] + red[2] + red[3]) * (1.0f / DIM) + REPS);
  float4 wv = *(const float4*)(wffn + tid * 4);
  float xn[4] = {v.x * rstd * wv.x, v.y * rstd * wv.y, v.z * rstd * wv.z,
                 v.w * rstd * wv.w};
  float pl[8] = {0, 0, 0, 0, 0, 0, 0, 0};
#pragma unroll
  for (int j = 0; j < 4; j++) {
    const float* gp = gw + (size_t)(tid * 4 + j) * 8;
    float4 g0 = *(const float4*)gp;
    float4 g1 = *(const float4*)(gp + 4);
    pl[0] += xn[j] * g0.x; pl[1] += xn[j] * g0.y;
    pl[2] += xn[j] * g0.z; pl[3] += xn[j] * g0.w;
    pl[4] += xn[j] * g1.x; pl[5] += xn[j] * g1.y;
    pl[6] += xn[j] * g1.z; pl[7] += xn[j] * g1.w;
  }
#pragma unroll
  for (int e = 0; e < 8; e++)
#pragma unroll
    for (int m = 1; m < 64; m <<= 1) pl[e] += __shfl_xor(pl[e], m);
  __shared__ float lred[4][8];
  if ((tid & 63) == 0)
#pragma unroll
    for (int e = 0; e < 8; e++) lred[tid >> 6][e] = pl[e];
  __syncthreads();
  if (tid == 0) {
    float lg[8];
#pragma unroll
    for (int e = 0; e < 8; e++)
      lg[e] = lred[0][e] + lred[1][e] + lred[2][e] + lred[3][e];
    int e1 = 0;
    float l1 = lg[0];
#pragma unroll
    for (int e = 1; e < 8; e++)
      if (lg[e] > l1) { l1 = lg[e]; e1 = e; }
    int e2 = -1;
    float l2 = -3.0e38f;
#pragma unroll
    for (int e = 0; e < 8; e++)
      if (e != e1 && lg[e] > l2) { l2 = lg[e]; e2 = e; }
    float w1 = 1.0f / (1.0f + expf(l2 - l1));
    float w2 = 1.0f / (1.0f + expf(l1 - l2));
    int p0 = atomicAdd(&cnt[e1], 1);
    pids[e1 * NPAIR + p0] = t * 2;
    pw[t * 2] = w1;
    int p1 = atomicAdd(&cnt[e2], 1);
    pids[e2 * NPAIR + p1] = t * 2 + 1;
    pw[t * 2 + 1] = w2;
  }
}

__global__ void zero_k(int* cnt) {
  if (threadIdx.x < 8) cnt[threadIdx.x] = 0;
}

__global__ void plan_k(const int* __restrict__ cnt, int* __restrict__ plan) {
  if (threadIdx.x == 0) {
    int acc = 0;
    for (int e = 0; e < 8; e++) {
      plan[e] = acc;
      acc += (cnt[e] + 127) >> 7;
    }
    plan[8] = acc;
  }
}

// ---------------- host launch ------------------------------------------------
extern "C" void kernel_launch(void* const* d_in, const int* in_sizes, int n_in,
                              void* d_out, int out_size, void* d_ws,
                              size_t ws_size, hipStream_t stream) {
  (void)in_sizes; (void)n_in; (void)out_size; (void)ws_size;
  const float* x = (const float*)d_in[0];
  const float* fc = (const float*)d_in[1];
  const float* fs = (const float*)d_in[2];
  const float* anw = (const float*)d_in[3];
  const float* fnw = (const float*)d_in[4];
  const float* wq = (const float*)d_in[5];
  const float* wk = (const float*)d_in[6];
  const float* wv = (const float*)d_in[7];
  const float* wo = (const float*)d_in[8];
  const float* gw = (const float*)d_in[9];
  const float* w1 = (const float*)d_in[10];
  const float* w2 = (const float*)d_in[11];
  const float* w3 = (const float*)d_in[12];
  float* outf = (float*)d_out;

  char* ws = (char*)d_ws;
  size_t off = 0;
  auto alloc = [&](size_t bytes) {
    void* p = ws + off;
    off += (bytes + 255) & ~(size_t)255;
    return p;
  };
  // xnh/xnl/qkvf region (41.2MB) is dead by MoE time; h13 dense (37.75MB)
  // overlays it.
  u16* xnh = (u16*)alloc((size_t)TOK * DIM * 2);
  u16* xnl = (u16*)alloc((size_t)TOK * DIM * 2);
  float* qkvf = (float*)alloc((size_t)TOK * NQKV * 4);
  u16* h13 = xnh;  // 72*128*2048*2 = 37.75MB <= 41.2MB region
  u16* wqkvT_h = (u16*)alloc((size_t)NQKV * DIM * 2);
  u16* wqkvT_l = (u16*)alloc((size_t)NQKV * DIM * 2);
  u16* woT_h = (u16*)alloc((size_t)DIM * DIM * 2);
  u16* woT_l = (u16*)alloc((size_t)DIM * DIM * 2);
  u16* w1T = (u16*)alloc((size_t)NE * FF * DIM * 2);
  u16* w3T = (u16*)alloc((size_t)NE * FF * DIM * 2);
  u16* w2T = (u16*)alloc((size_t)NE * DIM * FF * 2);
  u16* attnh = (u16*)alloc((size_t)TOK * DIM * 2);
  u16* attnl = (u16*)alloc((size_t)TOK * DIM * 2);
  float* hbuf = (float*)alloc((size_t)TOK * DIM * 4);
  u16* hn = (u16*)alloc((size_t)TOK * DIM * 2);
  int* cnt = (int*)alloc(64);
  int* plan = (int*)alloc(64);
  int* pids = (int*)alloc((size_t)NE * NPAIR * 4);
  float* pwbuf = (float*)alloc((size_t)NPAIR * 4);
  u16* Ksw_h = (u16*)alloc((size_t)NB * 4 * SEQ * 64 * 2);
  u16* Ksw_l = (u16*)alloc((size_t)NB * 4 * SEQ * 64 * 2);
  u16* Vsw_h = (u16*)alloc((size_t)NB * 4 * SEQ * 64 * 2);
  u16* Vsw_l = (u16*)alloc((size_t)NB * 4 * SEQ * 64 * 2);

  dim3 blk(256);
  hipLaunchKernelGGL((tcvt_k<true>), dim3(16, 16, 1), blk, 0, stream, wq,
                     wqkvT_h, wqkvT_l, 1024, 1024);
  hipLaunchKernelGGL((tcvt_k<true>), dim3(4, 16, 1), blk, 0, stream, wk,
                     wqkvT_h + 1024 * 1024, wqkvT_l + 1024 * 1024, 1024, 256);
  hipLaunchKernelGGL((tcvt_k<true>), dim3(4, 16, 1), blk, 0, stream, wv,
                     wqkvT_h + 1280 * 1024, wqkvT_l + 1280 * 1024, 1024, 256);
  hipLaunchKernelGGL((tcvt_k<true>), dim3(16, 16, 1), blk, 0, stream, wo, woT_h,
                     woT_l, 1024, 1024);
  hipLaunchKernelGGL((tcvt_k<false>), dim3(32, 16, 8), blk, 0, stream, w1, w1T,
                     (u16*)nullptr, 1024, 2048);
  hipLaunchKernelGGL((tcvt_k<false>), dim3(32, 16, 8), blk, 0, stream, w3, w3T,
                     (u16*)nullptr, 1024, 2048);
  hipLaunchKernelGGL((tcvt_k<false>), dim3(16, 32, 8), blk, 0, stream, w2, w2T,
                     (u16*)nullptr, 2048, 1024);
  hipLaunchKernelGGL((rmsnorm_k<true>), dim3(TOK), blk, 0, stream, x, anw, xnh,
                     xnl);
  // qkv projection: SPLIT, BN=64, dense grid (24 x 32 = 768, %8==0)
  hipLaunchKernelGGL((gemm_k<0, true, false, false, false, 0, 16, 64, 1, 3>),
                     dim3(NQKV / 64, TOK / 128, 1), blk, 0, stream, xnh, xnl,
                     wqkvT_h, wqkvT_l, (const u16*)nullptr, NQKV, NQKV, qkvf,
                     (u16*)nullptr, (float*)nullptr, (const float*)nullptr,
                     (const int*)nullptr, (const int*)nullptr,
                     (const float*)nullptr, (const int*)nullptr);
  hipLaunchKernelGGL(rope_k, dim3((TOK * 20 * 32) / 256), blk, 0, stream, qkvf,
                     fc, fs);
  hipLaunchKernelGGL(cvtkv_k, dim3(SEQ / 64, 4, NB), blk, 0, stream, qkvf,
                     Ksw_h, Ksw_l, Vsw_h, Vsw_l);
  hipLaunchKernelGGL(flash_k, dim3(16, NH, NB), blk, 0, stream, qkvf, Ksw_h,
                     Ksw_l, Vsw_h, Vsw_l, attnh, attnl);
  // output projection + residual: SPLIT, BN=64, dense grid (16 x 32 = 512)
  hipLaunchKernelGGL((gemm_k<1, true, false, false, false, 0, 16, 64, 1, 3>),
                     dim3(DIM / 64, TOK / 128, 1), blk, 0, stream, attnh, attnl,
                     woT_h, woT_l, (const u16*)nullptr, DIM, DIM, hbuf,
                     (u16*)nullptr, outf, x, (const int*)nullptr,
                     (const int*)nullptr, (const float*)nullptr,
                     (const int*)nullptr);
  hipLaunchKernelGGL((rmsnorm_k<false>), dim3(TOK), blk, 0, stream, hbuf, fnw,
                     hn, (u16*)nullptr);
  hipLaunchKernelGGL(zero_k, dim3(1), dim3(64), 0, stream, cnt);
  hipLaunchKernelGGL(route_k, dim3(TOK), blk, 0, stream, hbuf, fnw, gw, cnt,
                     pids, pwbuf);
  hipLaunchKernelGGL(plan_k, dim3(1), dim3(64), 0, stream, cnt, plan);
  // experts: h13 = silu(hn w1) * (hn w3) -> dense bf16  [persistent, DUAL,
  // NXL=4 (16 x-tiles), 1 item/block mostly, 3 blocks/CU]
  hipLaunchKernelGGL((gemm_k<2, false, true, true, true, 4, 16, 128, 1, 3>),
                     dim3(1024), blk, 0, stream, hn, (const u16*)nullptr, w1T,
                     (const u16*)nullptr, w3T, FF, FF, (float*)nullptr, h13,
                     (float*)nullptr, (const float*)nullptr, cnt, pids, pwbuf,
                     plan);
  // experts: out += w * (h13 w2)  [persistent, plain, K-split x2 (NKS=2),
  // NXL=4 (8 x-tiles x 2 ks), 4 blocks/CU]
  hipLaunchKernelGGL((gemm_k<3, false, false, true, false, 4, 16, 128, 2, 4>),
                     dim3(1152), blk, 0, stream, h13, (const u16*)nullptr, w2T,
                     (const u16*)nullptr, (const u16*)nullptr, DIM, DIM, outf,
                     (u16*)nullptr, (float*)nullptr, (const float*)nullptr, cnt,
                     pids, pwbuf, plan);
}

// Round 12
// 556.173 us; speedup vs baseline: 1.2726x; 1.2726x over previous
//
#include <hip/hip_runtime.h>
#include <stdint.h>

typedef unsigned short u16;
typedef unsigned int u32;
typedef __attribute__((ext_vector_type(8))) short short8;
typedef __attribute__((ext_vector_type(8))) u16 us8;
typedef __attribute__((ext_vector_type(4))) u16 us4;
typedef __attribute__((ext_vector_type(4))) float f32x4;

constexpr int NB = 2;
constexpr int SEQ = 2048;
constexpr int DIM = 1024;
constexpr int NH = 16;
constexpr int HD = 64;
constexpr int NE = 8;
constexpr int FF = 2048;
constexpr int TOK = NB * SEQ;      // 4096
constexpr int NQKV = 1536;         // q[0:1024) k[1024:1280) v[1280:1536)
constexpr int NPAIR = TOK * 2;     // 8192
constexpr float REPS = 1e-5f;

__device__ __forceinline__ u16 f2bf(float x) {
  union { float f; u32 u; } v; v.f = x;
  u32 r = v.u + 0x7fffu + ((v.u >> 16) & 1u);
  return (u16)(r >> 16);
}
__device__ __forceinline__ float bf2f(u16 h) {
  union { u32 u; float f; } v; v.u = ((u32)h) << 16;
  return v.f;
}

// async global->LDS, 16B per lane (HW: wave-uniform LDS base + lane*16)
__device__ __forceinline__ void gl_lds16(const u16* g, u16* l) {
  __builtin_amdgcn_global_load_lds(
      (const __attribute__((address_space(1))) void*)g,
      (__attribute__((address_space(3))) void*)l, 16, 0, 0);
}

// ---------------- weight transpose + fp32->bf16 (optionally split hi/lo) ----
template <bool SPLIT>
__global__ __launch_bounds__(256) void tcvt_k(const float* __restrict__ src,
                                              u16* __restrict__ dhi,
                                              u16* __restrict__ dlo,
                                              int K, int N) {
  int z = blockIdx.z;
  src += (size_t)z * K * N;
  dhi += (size_t)z * K * N;
  if (SPLIT) dlo += (size_t)z * K * N;
  int n0 = blockIdx.x * 64, k0 = blockIdx.y * 64;
  __shared__ float tile[64][65];
  int t = threadIdx.x;
  int kk = t >> 4, nn4 = (t & 15) * 4;
#pragma unroll
  for (int i = 0; i < 4; i++) {
    int k = kk + i * 16;
    const float* p = src + (size_t)(k0 + k) * N + n0 + nn4;
    float4 v = *(const float4*)p;
    tile[nn4 + 0][k] = v.x;
    tile[nn4 + 1][k] = v.y;
    tile[nn4 + 2][k] = v.z;
    tile[nn4 + 3][k] = v.w;
  }
  __syncthreads();
  int nn = t >> 4, k4 = (t & 15) * 4;
#pragma unroll
  for (int i = 0; i < 4; i++) {
    int n = nn + i * 16;
    us4 hi, lo;
#pragma unroll
    for (int j = 0; j < 4; j++) {
      float f = tile[n][k4 + j];
      u16 h = f2bf(f);
      hi[j] = h;
      if (SPLIT) lo[j] = f2bf(f - bf2f(h));
    }
    *(us4*)(dhi + (size_t)(n0 + n) * K + k0 + k4) = hi;
    if (SPLIT) *(us4*)(dlo + (size_t)(n0 + n) * K + k0 + k4) = lo;
  }
}

// ---------------- rmsnorm (fp32 in, bf16 out, optional split) ---------------
template <bool SPLIT>
__global__ __launch_bounds__(256) void rmsnorm_k(const float* __restrict__ x,
                                                 const float* __restrict__ w,
                                                 u16* __restrict__ ohi,
                                                 u16* __restrict__ olo) {
  int row = blockIdx.x, t = threadIdx.x;
  float4 v = *(const float4*)(x + (size_t)row * DIM + t * 4);
  float ss = v.x * v.x + v.y * v.y + v.z * v.z + v.w * v.w;
#pragma unroll
  for (int m = 1; m < 64; m <<= 1) ss += __shfl_xor(ss, m);
  __shared__ float red[4];
  if ((t & 63) == 0) red[t >> 6] = ss;
  __syncthreads();
  float rstd = rsqrtf((red[0] + red[1] + red[2] + red[3]) * (1.0f / DIM) + REPS);
  float4 wv = *(const float4*)(w + t * 4);
  float os[4] = {v.x * rstd * wv.x, v.y * rstd * wv.y, v.z * rstd * wv.z,
                 v.w * rstd * wv.w};
  us4 hi, lo;
#pragma unroll
  for (int j = 0; j < 4; j++) {
    u16 h = f2bf(os[j]);
    hi[j] = h;
    if (SPLIT) lo[j] = f2bf(os[j] - bf2f(h));
  }
  *(us4*)(ohi + (size_t)row * DIM + t * 4) = hi;
  if (SPLIT) *(us4*)(olo + (size_t)row * DIM + t * 4) = lo;
}

// ---------------- MFMA GEMM: m97 structure + XCD-chunked order + K-split ----
// LDS rows of 8 chunks x 16B; chunk position p of row r holds global chunk
// p^(r&7) (pre-swizzled source, linear LDS dest; conflict-free).
// 4 waves (2x2). XCD-chunked item order (blockIdx%8 = XCD owns contiguous
// range). NKS: K-split factor (only valid with atomic epilogue EPI=3).
// PERSIST: grid-strides over plan[] items. GATHER: A rows via pids (MoE).
// NOTE: __launch_bounds__(256,2) -- MINW>=3 caps VGPR below the 128-reg
// accumulator footprint and forces scratch spills (R11: WRITE 33->90MB).
template <int EPI, bool SPLIT, bool DUAL, bool PERSIST, bool GATHER, int NXL,
          int NT, int BN, int NKS>
__global__ __launch_bounds__(256, 2) void gemm_k(
    const u16* __restrict__ Ah, const u16* __restrict__ Al,
    const u16* __restrict__ Bh, const u16* __restrict__ Bl,
    const u16* __restrict__ Bd, int N, int ldc,
    float* __restrict__ Cf, u16* __restrict__ Cb, float* __restrict__ C2,
    const float* __restrict__ resid, const int* __restrict__ cnt,
    const int* __restrict__ pids, const float* __restrict__ pw,
    const int* __restrict__ plan) {
  constexpr int K = NT * 64;    // per-slice K
  constexpr int KT = K * NKS;   // full K (row stride)
  constexpr int WCOL = BN / 2;
  constexpr int FN = BN / 32;   // B frags per wave; also B staging iters

  int tid = threadIdx.x, lane = tid & 63, wid = tid >> 6;
  int wm = wid >> 1, wn = wid & 1;
  int rr = lane & 15, g = lane >> 4;

  __shared__ u16 sAh[128 * 64];
  __shared__ u16 sAl[SPLIT ? 128 * 64 : 16];
  __shared__ u16 sBh[BN * 64];
  __shared__ u16 sBl[SPLIT ? BN * 64 : 16];
  __shared__ u16 sB1[DUAL ? BN * 64 : 16];
  __shared__ int spid[PERSIST ? 128 : 8];
  __shared__ int srow[GATHER ? 128 : 8];

  int pl[9];
  int items;
  if (PERSIST) {
#pragma unroll
    for (int e = 0; e < 9; e++) pl[e] = plan[e];
    items = pl[8] << NXL;
  } else {
    items = 1;
  }

  // XCD-chunked virtual id: blocks on XCD i (blockIdx%8==i) process a
  // contiguous item/tile range. Requires grid size % 8 == 0 (all ours are).
  int it0, itstep;
  if (PERSIST) {
    int nb = gridDim.x;
    it0 = ((nb & 7) == 0) ? ((blockIdx.x & 7) * (nb >> 3) + (blockIdx.x >> 3))
                          : blockIdx.x;
    itstep = nb;
  } else {
    it0 = 0;
    itstep = 1;
  }
  for (int w = it0; w < items; w += itstep) {
    int m0, n0, z, yt, cntz, ks;
    if (PERSIST) {
      int wy = w >> NXL;
      int sub = w & ((1 << NXL) - 1);
      int x = sub / NKS;
      ks = sub % NKS;
      z = 0;
#pragma unroll
      for (int e = 1; e < 8; e++) z += (wy >= pl[e]) ? 1 : 0;
      yt = wy - pl[z];
      m0 = wy * 128;  // dense row base
      n0 = x * BN;
      cntz = cnt[z];
      __syncthreads();  // previous item done with spid/srow + LDS
      if (tid < 128) {
        int i = yt * 128 + tid;
        if (i > cntz - 1) i = cntz - 1;
        int p = pids[z * NPAIR + i];
        spid[tid] = p;
        if (GATHER) srow[tid] = p >> 1;
      }
      __syncthreads();
    } else {
      int gx = gridDim.x;
      int nb = gx * gridDim.y;
      int lin = blockIdx.y * gx + blockIdx.x;
      int v = ((nb & 7) == 0) ? ((lin & 7) * (nb >> 3) + (lin >> 3)) : lin;
      m0 = (v / gx) * 128;
      n0 = (v % gx) * BN;
      z = 0;
      yt = 0;
      cntz = 1 << 30;
      ks = 0;
    }

    const u16* Bhz = Bh + (size_t)z * N * KT;
    const u16* Blz = SPLIT ? Bl + (size_t)z * N * KT : nullptr;
    const u16* Bdz = DUAL ? Bd + (size_t)z * N * KT : nullptr;
    int kbase = ks * K;

    // staging descriptors (pre-swizzled global source, linear LDS dest)
    const u16 *agh[4], *agl[SPLIT ? 4 : 1];
    int aoff[4];
#pragma unroll
    for (int i = 0; i < 4; i++) {
      int cid = tid + i * 256;
      int r = cid >> 3, c = cid & 7;
      int gr = GATHER ? srow[r] : (m0 + r);
      int sc = c ^ (r & 7);
      agh[i] = Ah + (size_t)gr * KT + kbase + sc * 8;
      if (SPLIT) agl[i] = Al + (size_t)gr * KT + kbase + sc * 8;
      aoff[i] = r * 64 + c * 8;
    }
    const u16 *bgh[FN], *bgl[SPLIT ? FN : 1], *bg1[DUAL ? FN : 1];
    int boff[FN];
#pragma unroll
    for (int i = 0; i < FN; i++) {
      int cid = tid + i * 256;
      int r = cid >> 3, c = cid & 7;
      int sc = c ^ (r & 7);
      size_t gr = (size_t)(n0 + r) * KT + kbase + sc * 8;
      bgh[i] = Bhz + gr;
      if (SPLIT) bgl[i] = Blz + gr;
      if (DUAL) bg1[i] = Bdz + gr;
      boff[i] = r * 64 + c * 8;
    }

    f32x4 zv = {0.f, 0.f, 0.f, 0.f};
    f32x4 acc[4][FN];
    f32x4 acc1[DUAL ? 4 : 1][DUAL ? FN : 1];
#pragma unroll
    for (int a = 0; a < 4; a++)
#pragma unroll
      for (int b = 0; b < FN; b++) {
        acc[a][b] = zv;
        if (DUAL) acc1[a][b] = zv;
      }

    for (int t = 0; t < NT; t++) {
      int k0 = t * 64;
      __syncthreads();  // previous compute done reading LDS
#pragma unroll
      for (int i = 0; i < 4; i++) {
        gl_lds16(agh[i] + k0, sAh + aoff[i]);
        if (SPLIT) gl_lds16(agl[i] + k0, sAl + aoff[i]);
      }
#pragma unroll
      for (int i = 0; i < FN; i++) {
        gl_lds16(bgh[i] + k0, sBh + boff[i]);
        if (SPLIT) gl_lds16(bgl[i] + k0, sBl + boff[i]);
        if (DUAL) gl_lds16(bg1[i] + k0, sB1 + boff[i]);
      }
      __syncthreads();  // compiler drains vmcnt(0) before this barrier

#pragma unroll
      for (int kc = 0; kc < 2; kc++) {
        short8 a_h[4], a_l[SPLIT ? 4 : 1], b_h[FN], b_l[SPLIT ? FN : 1],
            b1f[DUAL ? FN : 1];
#pragma unroll
        for (int f = 0; f < 4; f++) {
          int ra = wm * 64 + f * 16 + rr;
          int off = ra * 64 + (((kc * 4 + g) ^ (ra & 7)) * 8);
          a_h[f] = *(const short8*)&sAh[off];
          if (SPLIT) a_l[f] = *(const short8*)&sAl[off];
        }
#pragma unroll
        for (int f = 0; f < FN; f++) {
          int rb = wn * WCOL + f * 16 + rr;
          int off = rb * 64 + (((kc * 4 + g) ^ (rb & 7)) * 8);
          b_h[f] = *(const short8*)&sBh[off];
          if (SPLIT) b_l[f] = *(const short8*)&sBl[off];
          if (DUAL) b1f[f] = *(const short8*)&sB1[off];
        }
#pragma unroll
        for (int fm = 0; fm < 4; fm++)
#pragma unroll
          for (int fn = 0; fn < FN; fn++) {
            acc[fm][fn] = __builtin_amdgcn_mfma_f32_16x16x32_bf16(
                a_h[fm], b_h[fn], acc[fm][fn], 0, 0, 0);
            if (SPLIT) {
              acc[fm][fn] = __builtin_amdgcn_mfma_f32_16x16x32_bf16(
                  a_h[fm], b_l[fn], acc[fm][fn], 0, 0, 0);
              acc[fm][fn] = __builtin_amdgcn_mfma_f32_16x16x32_bf16(
                  a_l[fm], b_h[fn], acc[fm][fn], 0, 0, 0);
            }
            if (DUAL)
              acc1[fm][fn] = __builtin_amdgcn_mfma_f32_16x16x32_bf16(
                  a_h[fm], b1f[fn], acc1[fm][fn], 0, 0, 0);
          }
      }
    }

    // epilogue: C frag layout col=lane&15, row=(lane>>4)*4+reg
#pragma unroll
    for (int fm = 0; fm < 4; fm++)
#pragma unroll
      for (int fn = 0; fn < FN; fn++)
#pragma unroll
        for (int rg = 0; rg < 4; rg++) {
          int rl = wm * 64 + fm * 16 + g * 4 + rg;
          int col = n0 + wn * WCOL + fn * 16 + rr;
          float v = acc[fm][fn][rg];
          if (EPI == 0) {
            Cf[(size_t)(m0 + rl) * ldc + col] = v;
          } else if (EPI == 1) {
            size_t idx = (size_t)(m0 + rl) * ldc + col;
            float r2 = v + resid[idx];
            Cf[idx] = r2;
            C2[idx] = r2;
          } else if (EPI == 2) {
            float gg = v / (1.0f + __expf(-v));
            float o = gg * acc1[fm][fn][rg];
            Cb[(size_t)(m0 + rl) * ldc + col] = f2bf(o);
          } else {
            int i = yt * 128 + rl;
            if (i < cntz) {
              int p = spid[rl];
              atomicAdd(&Cf[(size_t)(p >> 1) * ldc + col], pw[p] * v);
            }
          }
        }
  }
}

// ---------------- RoPE (in-place on fp32 qkv: 16 q heads + 4 k heads) -------
__global__ __launch_bounds__(256) void rope_k(float* __restrict__ qkv,
                                              const float* __restrict__ fc,
                                              const float* __restrict__ fs) {
  int idx = blockIdx.x * 256 + threadIdx.x;
  int i = idx & 31;
  int hh = (idx >> 5) % 20;
  int t = idx / 640;
  if (t >= TOK) return;
  int s = t & (SEQ - 1);
  int base = (hh < 16) ? (hh * 64) : (1024 + (hh - 16) * 64);
  float c = fc[s * 32 + i], sn = fs[s * 32 + i];
  float* p = qkv + (size_t)t * NQKV + base + 2 * i;
  float xr = p[0], xi = p[1];
  p[0] = xr * c - xi * sn;
  p[1] = xr * sn + xi * c;
}

// ---------------- K/V convert to split bf16, pre-swizzled tile-major --------
__global__ __launch_bounds__(256) void cvtkv_k(const float* __restrict__ qkv,
                                               u16* __restrict__ Kh,
                                               u16* __restrict__ Kl,
                                               u16* __restrict__ Vh,
                                               u16* __restrict__ Vl) {
  int kvt = blockIdx.x;
  int kvh = blockIdx.y;
  int b = blockIdx.z;
  int t = threadIdx.x;
  __shared__ float vt[64][65];
  size_t tile = ((size_t)((b * 4 + kvh) * 32 + kvt)) * 4096;
  int r = t >> 2, c4 = t & 3;
  {
    const float* kp = qkv + ((size_t)(b * SEQ + kvt * 64 + r)) * NQKV + 1024 +
                      kvh * 64 + c4 * 16;
    float ff[16];
#pragma unroll
    for (int q = 0; q < 4; q++) {
      float4 f = *(const float4*)(kp + q * 4);
      ff[q * 4 + 0] = f.x; ff[q * 4 + 1] = f.y;
      ff[q * 4 + 2] = f.z; ff[q * 4 + 3] = f.w;
    }
#pragma unroll
    for (int half = 0; half < 2; half++) {
      int c = c4 * 2 + half;
      us8 hi, lo;
#pragma unroll
      for (int j = 0; j < 8; j++) {
        float f = ff[half * 8 + j];
        u16 h = f2bf(f);
        hi[j] = h;
        lo[j] = f2bf(f - bf2f(h));
      }
      int off = r * 64 + ((c ^ (r & 7)) * 8);
      *(us8*)(Kh + tile + off) = hi;
      *(us8*)(Kl + tile + off) = lo;
    }
  }
  {
    const float* vp = qkv + ((size_t)(b * SEQ + kvt * 64 + r)) * NQKV + 1280 +
                      kvh * 64 + c4 * 16;
#pragma unroll
    for (int q = 0; q < 4; q++) {
      float4 f = *(const float4*)(vp + q * 4);
      vt[r][c4 * 16 + q * 4 + 0] = f.x;
      vt[r][c4 * 16 + q * 4 + 1] = f.y;
      vt[r][c4 * 16 + q * 4 + 2] = f.z;
      vt[r][c4 * 16 + q * 4 + 3] = f.w;
    }
  }
  __syncthreads();
  {
    int d = t >> 2, g4 = t & 3;
    float ff[16];
#pragma unroll
    for (int j = 0; j < 16; j++) ff[j] = vt[g4 * 16 + j][d];
#pragma unroll
    for (int half = 0; half < 2; half++) {
      int c = g4 * 2 + half;
      us8 hi, lo;
#pragma unroll
      for (int j = 0; j < 8; j++) {
        float f = ff[half * 8 + j];
        u16 h = f2bf(f);
        hi[j] = h;
        lo[j] = f2bf(f - bf2f(h));
      }
      int off = d * 64 + ((c ^ (d & 7)) * 8);
      *(us8*)(Vh + tile + off) = hi;
      *(us8*)(Vl + tile + off) = lo;
    }
  }
}

// ---------------- flash attention (paired q-tiles, preconverted K/V) --------
__global__ __launch_bounds__(256, 2) void flash_k(
    const float* __restrict__ qkv, const u16* __restrict__ Kg,
    const u16* __restrict__ Klg, const u16* __restrict__ Vg,
    const u16* __restrict__ Vlg, u16* __restrict__ ah, u16* __restrict__ al) {
  int pi = blockIdx.x;
  int h = blockIdx.y;
  int b = blockIdx.z;
  int qt[2] = {31 - pi, pi};
  int kvh = h >> 2;
  int tid = threadIdx.x, lane = tid & 63, wid = tid >> 6;
  int rr = lane & 15, g = lane >> 4;

  __shared__ u16 sKh[4096], sKl[4096], sVh[4096], sVl[4096];
  __shared__ u32 sP[4][1024];

  f32x4 zv = {0.f, 0.f, 0.f, 0.f};
  short8 aqh[2][2], aql[2][2];
#pragma unroll
  for (int u = 0; u < 2; u++) {
    int qrow = qt[u] * 64 + wid * 16 + rr;
    const float* qp =
        qkv + ((size_t)(b * SEQ + qrow)) * NQKV + h * 64 + g * 8;
#pragma unroll
    for (int kc = 0; kc < 2; kc++) {
      float4 f0 = *(const float4*)(qp + kc * 32);
      float4 f1 = *(const float4*)(qp + kc * 32 + 4);
      float ff[8] = {f0.x, f0.y, f0.z, f0.w, f1.x, f1.y, f1.z, f1.w};
#pragma unroll
      for (int j = 0; j < 8; j++) {
        u16 hi = f2bf(ff[j]);
        aqh[u][kc][j] = (short)hi;
        aql[u][kc][j] = (short)f2bf(ff[j] - bf2f(hi));
      }
    }
  }

  f32x4 o[2][4];
  float m_r[2][4], l_r[2][4];
#pragma unroll
  for (int u = 0; u < 2; u++)
#pragma unroll
    for (int i = 0; i < 4; i++) {
      o[u][i] = zv;
      m_r[u][i] = -3.0e38f;
      l_r[u][i] = 0.f;
    }

  size_t tb = ((size_t)(b * 4 + kvh) * 32) * 4096;
  int so = tid * 16;
  us8 rKh[2], rKl[2], rVh[2], rVl[2];
  {
    size_t go = tb + so;
    rKh[0] = *(const us8*)(Kg + go);  rKh[1] = *(const us8*)(Kg + go + 8);
    rKl[0] = *(const us8*)(Klg + go); rKl[1] = *(const us8*)(Klg + go + 8);
    rVh[0] = *(const us8*)(Vg + go);  rVh[1] = *(const us8*)(Vg + go + 8);
    rVl[0] = *(const us8*)(Vlg + go); rVl[1] = *(const us8*)(Vlg + go + 8);
  }

  int nt = qt[0];
  for (int kvt = 0; kvt <= nt; kvt++) {
    __syncthreads();
    *(us8*)&sKh[so] = rKh[0]; *(us8*)&sKh[so + 8] = rKh[1];
    *(us8*)&sKl[so] = rKl[0]; *(us8*)&sKl[so + 8] = rKl[1];
    *(us8*)&sVh[so] = rVh[0]; *(us8*)&sVh[so + 8] = rVh[1];
    *(us8*)&sVl[so] = rVl[0]; *(us8*)&sVl[so + 8] = rVl[1];
    if (kvt < nt) {
      size_t go = tb + (size_t)(kvt + 1) * 4096 + so;
      rKh[0] = *(const us8*)(Kg + go);  rKh[1] = *(const us8*)(Kg + go + 8);
      rKl[0] = *(const us8*)(Klg + go); rKl[1] = *(const us8*)(Klg + go + 8);
      rVh[0] = *(const us8*)(Vg + go);  rVh[1] = *(const us8*)(Vg + go + 8);
      rVl[0] = *(const us8*)(Vlg + go); rVl[1] = *(const us8*)(Vlg + go + 8);
    }
    __syncthreads();

#pragma unroll
    for (int u = 0; u < 2; u++) {
      if (!(u == 1 && kvt > qt[1])) {
        float pv[4][4];
#pragma unroll
        for (int c16 = 0; c16 < 4; c16++) {
          int rk = c16 * 16 + rr;
          f32x4 sacc = zv;
#pragma unroll
          for (int kc = 0; kc < 2; kc++) {
            int sw = rk * 64 + (((kc * 4 + g) ^ (rk & 7)) * 8);
            short8 bh = *(const short8*)&sKh[sw];
            short8 bl = *(const short8*)&sKl[sw];
            sacc = __builtin_amdgcn_mfma_f32_16x16x32_bf16(aqh[u][kc], bh,
                                                           sacc, 0, 0, 0);
            sacc = __builtin_amdgcn_mfma_f32_16x16x32_bf16(aqh[u][kc], bl,
                                                           sacc, 0, 0, 0);
            sacc = __builtin_amdgcn_mfma_f32_16x16x32_bf16(aql[u][kc], bh,
                                                           sacc, 0, 0, 0);
          }
          bool diag = (kvt == qt[u]);
#pragma unroll
          for (int rg = 0; rg < 4; rg++) {
            float val = sacc[rg] * 0.125f;
            if (diag) {
              int kv_l = c16 * 16 + rr;
              int q_l = wid * 16 + g * 4 + rg;
              if (kv_l > q_l) val = -3.0e38f;
            }
            pv[c16][rg] = val;
          }
        }
        float pm[4];
#pragma unroll
        for (int rg = 0; rg < 4; rg++)
          pm[rg] = fmaxf(fmaxf(pv[0][rg], pv[1][rg]),
                         fmaxf(pv[2][rg], pv[3][rg]));
#pragma unroll
        for (int m = 1; m < 16; m <<= 1)
#pragma unroll
          for (int rg = 0; rg < 4; rg++)
            pm[rg] = fmaxf(pm[rg], __shfl_xor(pm[rg], m));
        float scl[4];
#pragma unroll
        for (int rg = 0; rg < 4; rg++) {
          float mn = fmaxf(m_r[u][rg], pm[rg]);
          scl[rg] = __expf(m_r[u][rg] - mn);
          m_r[u][rg] = mn;
        }
#pragma unroll
        for (int c16 = 0; c16 < 4; c16++)
#pragma unroll
          for (int rg = 0; rg < 4; rg++)
            pv[c16][rg] = __expf(pv[c16][rg] - m_r[u][rg]);
        float rsum[4];
#pragma unroll
        for (int rg = 0; rg < 4; rg++)
          rsum[rg] = pv[0][rg] + pv[1][rg] + pv[2][rg] + pv[3][rg];
#pragma unroll
        for (int m = 1; m < 16; m <<= 1)
#pragma unroll
          for (int rg = 0; rg < 4; rg++) rsum[rg] += __shfl_xor(rsum[rg], m);
#pragma unroll
        for (int rg = 0; rg < 4; rg++)
          l_r[u][rg] = l_r[u][rg] * scl[rg] + rsum[rg];
#pragma unroll
        for (int d16 = 0; d16 < 4; d16++)
#pragma unroll
          for (int rg = 0; rg < 4; rg++) o[u][d16][rg] *= scl[rg];

#pragma unroll
        for (int c16 = 0; c16 < 4; c16++)
#pragma unroll
          for (int rg = 0; rg < 4; rg++) {
            int ql = g * 4 + rg;
            int kvl = c16 * 16 + rr;
            u16 hi = f2bf(pv[c16][rg]);
            u16 lo = f2bf(pv[c16][rg] - bf2f(hi));
            sP[wid][ql * 64 + (kvl ^ (((ql >> 2) & 3) << 4))] =
                ((u32)lo << 16) | (u32)hi;
          }
        short8 pah[2], pal[2];
#pragma unroll
        for (int kc = 0; kc < 2; kc++) {
          int xb = (kc * 32 + g * 8) ^ (((rr >> 2) & 3) << 4);
          const u32* pp = &sP[wid][rr * 64 + xb];
#pragma unroll
          for (int j = 0; j < 8; j++) {
            u32 w = pp[j];
            pah[kc][j] = (short)(w & 0xffffu);
            pal[kc][j] = (short)(w >> 16);
          }
        }
#pragma unroll
        for (int d16 = 0; d16 < 4; d16++) {
          int rv = d16 * 16 + rr;
#pragma unroll
          for (int kc = 0; kc < 2; kc++) {
            int sw = rv * 64 + (((kc * 4 + g) ^ (rv & 7)) * 8);
            short8 vh = *(const short8*)&sVh[sw];
            short8 vl = *(const short8*)&sVl[sw];
            o[u][d16] = __builtin_amdgcn_mfma_f32_16x16x32_bf16(
                pah[kc], vh, o[u][d16], 0, 0, 0);
            o[u][d16] = __builtin_amdgcn_mfma_f32_16x16x32_bf16(
                pah[kc], vl, o[u][d16], 0, 0, 0);
            o[u][d16] = __builtin_amdgcn_mfma_f32_16x16x32_bf16(
                pal[kc], vh, o[u][d16], 0, 0, 0);
          }
        }
      }
    }
  }

#pragma unroll
  for (int u = 0; u < 2; u++)
#pragma unroll
    for (int rg = 0; rg < 4; rg++) {
      float inv = 1.0f / l_r[u][rg];
      int qr = qt[u] * 64 + wid * 16 + g * 4 + rg;
      size_t obase = (size_t)(b * SEQ + qr) * 1024 + h * 64;
#pragma unroll
      for (int d16 = 0; d16 < 4; d16++) {
        float v = o[u][d16][rg] * inv;
        u16 hi = f2bf(v);
        ah[obase + d16 * 16 + rr] = hi;
        al[obase + d16 * 16 + rr] = f2bf(v - bf2f(hi));
      }
    }
}

// ---------------- routing: fp32 rmsnorm + gate + top2 + atomic bucketing ----
__global__ __launch_bounds__(256) void route_k(const float* __restrict__ h,
                                               const float* __restrict__ wffn,
                                               const float* __restrict__ gw,
                                               int* __restrict__ cnt,
                                               int* __restrict__ pids,
                                               float* __restrict__ pw) {
  int t = blockIdx.x, tid = threadIdx.x;
  float4 v = *(const float4*)(h + (size_t)t * DIM + tid * 4);
  float ss = v.x * v.x + v.y * v.y + v.z * v.z + v.w * v.w;
#pragma unroll
  for (int m = 1; m < 64; m <<= 1) ss += __shfl_xor(ss, m);
  __shared__ float red[4];
  if ((tid & 63) == 0) red[tid >> 6] = ss;
  __syncthreads();
  float rstd = rsqrtf((red[0] + red[1] + red[2] + red[3]) * (1.0f / DIM) + REPS);
  float4 wv = *(const float4*)(wffn + tid * 4);
  float xn[4] = {v.x * rstd * wv.x, v.y * rstd * wv.y, v.z * rstd * wv.z,
                 v.w * rstd * wv.w};
  float pl[8] = {0, 0, 0, 0, 0, 0, 0, 0};
#pragma unroll
  for (int j = 0; j < 4; j++) {
    const float* gp = gw + (size_t)(tid * 4 + j) * 8;
    float4 g0 = *(const float4*)gp;
    float4 g1 = *(const float4*)(gp + 4);
    pl[0] += xn[j] * g0.x; pl[1] += xn[j] * g0.y;
    pl[2] += xn[j] * g0.z; pl[3] += xn[j] * g0.w;
    pl[4] += xn[j] * g1.x; pl[5] += xn[j] * g1.y;
    pl[6] += xn[j] * g1.z; pl[7] += xn[j] * g1.w;
  }
#pragma unroll
  for (int e = 0; e < 8; e++)
#pragma unroll
    for (int m = 1; m < 64; m <<= 1) pl[e] += __shfl_xor(pl[e], m);
  __shared__ float lred[4][8];
  if ((tid & 63) == 0)
#pragma unroll
    for (int e = 0; e < 8; e++) lred[tid >> 6][e] = pl[e];
  __syncthreads();
  if (tid == 0) {
    float lg[8];
#pragma unroll
    for (int e = 0; e < 8; e++)
      lg[e] = lred[0][e] + lred[1][e] + lred[2][e] + lred[3][e];
    int e1 = 0;
    float l1 = lg[0];
#pragma unroll
    for (int e = 1; e < 8; e++)
      if (lg[e] > l1) { l1 = lg[e]; e1 = e; }
    int e2 = -1;
    float l2 = -3.0e38f;
#pragma unroll
    for (int e = 0; e < 8; e++)
      if (e != e1 && lg[e] > l2) { l2 = lg[e]; e2 = e; }
    float w1 = 1.0f / (1.0f + expf(l2 - l1));
    float w2 = 1.0f / (1.0f + expf(l1 - l2));
    int p0 = atomicAdd(&cnt[e1], 1);
    pids[e1 * NPAIR + p0] = t * 2;
    pw[t * 2] = w1;
    int p1 = atomicAdd(&cnt[e2], 1);
    pids[e2 * NPAIR + p1] = t * 2 + 1;
    pw[t * 2 + 1] = w2;
  }
}

__global__ void zero_k(int* cnt) {
  if (threadIdx.x < 8) cnt[threadIdx.x] = 0;
}

__global__ void plan_k(const int* __restrict__ cnt, int* __restrict__ plan) {
  if (threadIdx.x == 0) {
    int acc = 0;
    for (int e = 0; e < 8; e++) {
      plan[e] = acc;
      acc += (cnt[e] + 127) >> 7;
    }
    plan[8] = acc;
  }
}

// ---------------- host launch ------------------------------------------------
extern "C" void kernel_launch(void* const* d_in, const int* in_sizes, int n_in,
                              void* d_out, int out_size, void* d_ws,
                              size_t ws_size, hipStream_t stream) {
  (void)in_sizes; (void)n_in; (void)out_size; (void)ws_size;
  const float* x = (const float*)d_in[0];
  const float* fc = (const float*)d_in[1];
  const float* fs = (const float*)d_in[2];
  const float* anw = (const float*)d_in[3];
  const float* fnw = (const float*)d_in[4];
  const float* wq = (const float*)d_in[5];
  const float* wk = (const float*)d_in[6];
  const float* wv = (const float*)d_in[7];
  const float* wo = (const float*)d_in[8];
  const float* gw = (const float*)d_in[9];
  const float* w1 = (const float*)d_in[10];
  const float* w2 = (const float*)d_in[11];
  const float* w3 = (const float*)d_in[12];
  float* outf = (float*)d_out;

  char* ws = (char*)d_ws;
  size_t off = 0;
  auto alloc = [&](size_t bytes) {
    void* p = ws + off;
    off += (bytes + 255) & ~(size_t)255;
    return p;
  };
  // xnh/xnl/qkvf region (41.2MB) is dead by MoE time; h13 dense (37.75MB)
  // overlays it.
  u16* xnh = (u16*)alloc((size_t)TOK * DIM * 2);
  u16* xnl = (u16*)alloc((size_t)TOK * DIM * 2);
  float* qkvf = (float*)alloc((size_t)TOK * NQKV * 4);
  u16* h13 = xnh;  // 72*128*2048*2 = 37.75MB <= 41.2MB region
  u16* wqkvT_h = (u16*)alloc((size_t)NQKV * DIM * 2);
  u16* wqkvT_l = (u16*)alloc((size_t)NQKV * DIM * 2);
  u16* woT_h = (u16*)alloc((size_t)DIM * DIM * 2);
  u16* woT_l = (u16*)alloc((size_t)DIM * DIM * 2);
  u16* w1T = (u16*)alloc((size_t)NE * FF * DIM * 2);
  u16* w3T = (u16*)alloc((size_t)NE * FF * DIM * 2);
  u16* w2T = (u16*)alloc((size_t)NE * DIM * FF * 2);
  u16* attnh = (u16*)alloc((size_t)TOK * DIM * 2);
  u16* attnl = (u16*)alloc((size_t)TOK * DIM * 2);
  float* hbuf = (float*)alloc((size_t)TOK * DIM * 4);
  u16* hn = (u16*)alloc((size_t)TOK * DIM * 2);
  int* cnt = (int*)alloc(64);
  int* plan = (int*)alloc(64);
  int* pids = (int*)alloc((size_t)NE * NPAIR * 4);
  float* pwbuf = (float*)alloc((size_t)NPAIR * 4);
  u16* Ksw_h = (u16*)alloc((size_t)NB * 4 * SEQ * 64 * 2);
  u16* Ksw_l = (u16*)alloc((size_t)NB * 4 * SEQ * 64 * 2);
  u16* Vsw_h = (u16*)alloc((size_t)NB * 4 * SEQ * 64 * 2);
  u16* Vsw_l = (u16*)alloc((size_t)NB * 4 * SEQ * 64 * 2);

  dim3 blk(256);
  hipLaunchKernelGGL((tcvt_k<true>), dim3(16, 16, 1), blk, 0, stream, wq,
                     wqkvT_h, wqkvT_l, 1024, 1024);
  hipLaunchKernelGGL((tcvt_k<true>), dim3(4, 16, 1), blk, 0, stream, wk,
                     wqkvT_h + 1024 * 1024, wqkvT_l + 1024 * 1024, 1024, 256);
  hipLaunchKernelGGL((tcvt_k<true>), dim3(4, 16, 1), blk, 0, stream, wv,
                     wqkvT_h + 1280 * 1024, wqkvT_l + 1280 * 1024, 1024, 256);
  hipLaunchKernelGGL((tcvt_k<true>), dim3(16, 16, 1), blk, 0, stream, wo, woT_h,
                     woT_l, 1024, 1024);
  hipLaunchKernelGGL((tcvt_k<false>), dim3(32, 16, 8), blk, 0, stream, w1, w1T,
                     (u16*)nullptr, 1024, 2048);
  hipLaunchKernelGGL((tcvt_k<false>), dim3(32, 16, 8), blk, 0, stream, w3, w3T,
                     (u16*)nullptr, 1024, 2048);
  hipLaunchKernelGGL((tcvt_k<false>), dim3(16, 32, 8), blk, 0, stream, w2, w2T,
                     (u16*)nullptr, 2048, 1024);
  hipLaunchKernelGGL((rmsnorm_k<true>), dim3(TOK), blk, 0, stream, x, anw, xnh,
                     xnl);
  // qkv projection: SPLIT, BN=64, dense grid (24 x 32 = 768, %8==0)
  hipLaunchKernelGGL((gemm_k<0, true, false, false, false, 0, 16, 64, 1>),
                     dim3(NQKV / 64, TOK / 128, 1), blk, 0, stream, xnh, xnl,
                     wqkvT_h, wqkvT_l, (const u16*)nullptr, NQKV, NQKV, qkvf,
                     (u16*)nullptr, (float*)nullptr, (const float*)nullptr,
                     (const int*)nullptr, (const int*)nullptr,
                     (const float*)nullptr, (const int*)nullptr);
  hipLaunchKernelGGL(rope_k, dim3((TOK * 20 * 32) / 256), blk, 0, stream, qkvf,
                     fc, fs);
  hipLaunchKernelGGL(cvtkv_k, dim3(SEQ / 64, 4, NB), blk, 0, stream, qkvf,
                     Ksw_h, Ksw_l, Vsw_h, Vsw_l);
  hipLaunchKernelGGL(flash_k, dim3(16, NH, NB), blk, 0, stream, qkvf, Ksw_h,
                     Ksw_l, Vsw_h, Vsw_l, attnh, attnl);
  // output projection + residual: SPLIT, BN=64, dense grid (16 x 32 = 512)
  hipLaunchKernelGGL((gemm_k<1, true, false, false, false, 0, 16, 64, 1>),
                     dim3(DIM / 64, TOK / 128, 1), blk, 0, stream, attnh, attnl,
                     woT_h, woT_l, (const u16*)nullptr, DIM, DIM, hbuf,
                     (u16*)nullptr, outf, x, (const int*)nullptr,
                     (const int*)nullptr, (const float*)nullptr,
                     (const int*)nullptr);
  hipLaunchKernelGGL((rmsnorm_k<false>), dim3(TOK), blk, 0, stream, hbuf, fnw,
                     hn, (u16*)nullptr);
  hipLaunchKernelGGL(zero_k, dim3(1), dim3(64), 0, stream, cnt);
  hipLaunchKernelGGL(route_k, dim3(TOK), blk, 0, stream, hbuf, fnw, gw, cnt,
                     pids, pwbuf);
  hipLaunchKernelGGL(plan_k, dim3(1), dim3(64), 0, stream, cnt, plan);
  // experts: h13 = silu(hn w1) * (hn w3) -> dense bf16  [persistent, DUAL,
  // NXL=4 (16 x-tiles), ~1 item/block]
  hipLaunchKernelGGL((gemm_k<2, false, true, true, true, 4, 16, 128, 1>),
                     dim3(1024), blk, 0, stream, hn, (const u16*)nullptr, w1T,
                     (const u16*)nullptr, w3T, FF, FF, (float*)nullptr, h13,
                     (float*)nullptr, (const float*)nullptr, cnt, pids, pwbuf,
                     plan);
  // experts: out += w * (h13 w2)  [persistent, plain, K-split x2 (NKS=2),
  // NXL=4 (8 x-tiles x 2 ks)]
  hipLaunchKernelGGL((gemm_k<3, false, false, true, false, 4, 16, 128, 2>),
                     dim3(1152), blk, 0, stream, h13, (const u16*)nullptr, w2T,
                     (const u16*)nullptr, (const u16*)nullptr, DIM, DIM, outf,
                     (u16*)nullptr, (float*)nullptr, (const float*)nullptr, cnt,
                     pids, pwbuf, plan);
}